// Round 1
// 929.338 us; speedup vs baseline: 1.0382x; 1.0382x over previous
//
#include <hip/hip_runtime.h>
#include <hip/hip_bf16.h>
#include <stdint.h>

// ============================================================================
// Attn_50233937494279: qb=q@Win^T; S=softmax(qb@c^T); ctx=S@c;
//                      out=tanh([ctx|qb]@Wout^T); returns (out[q,b,d], S[b,q,k])
//
// R2 -> R3: gemm_kernel rewritten from the 128^2/2-barrier (m97) structure
// (~860 TF effective, MfmaUtil 36%) to a 256^2-tile counted-vmcnt pipeline
// (T3+T4+T5):
//   - 512 threads = 8 waves (2M x 4N), per-wave 128x64 output (acc[8][4]).
//   - BK=32, LDS ring of 4 K-tile buffers (4 x (16KB A + 16KB B) = 128 KiB),
//     prefetch depth 3: iteration t stages tile t+3, waits s_waitcnt vmcnt(8)
//     (3 tiles x 4 loads/thread in flight, retire only tile t), ONE s_barrier
//     per K-step. vmcnt(0) only at the final tile.
//     Race-freedom: slot t&3 is overwritten by tile t+4 staged at iteration
//     t+1 AFTER that iteration's barrier; all waves' ds_reads of tile t
//     retired (lgkmcnt before their MFMAs) before reaching that barrier.
//   - SPLIT=1 (3-term bf16 emulation) is expressed as a virtual-K plain GEMM:
//     K -> 3K, tile vt = (k=vt/3, term=vt%3) with (Ah,Bh),(Ah,Bl),(Al,Bh) --
//     hi/lo panels fetched at the same k back-to-back (L1/L2 reuse).
//   - s_setprio(1/0) around the MFMA cluster; sched_barrier(0) fences.
//
// Precision: GEMM1/GEMM2 (pre-softmax) 3-term split-bf16; G4/G5 plain bf16.
// Workspace layout (200 MB), region reuse across stream-ordered phases:
//   A @ 0      (64MB): q_hi -> c_hi (after G1) -> p_bf16 (after G2)
//   B @ 64MB   (64MB): qb_hi+qb_lo -> ct (c transposed, after G2)
//   C @ 128MB  (64MB): cat = [ctx | qb] bf16
//   W @ 192MB  ( 8MB): Win_hi, Win_lo, Wout_bf16
//   d_out out-region (64MB, unused until G5): q_lo -> c_lo scratch
// ============================================================================

typedef __bf16 bf16x8 __attribute__((ext_vector_type(8)));
typedef float floatx4 __attribute__((ext_vector_type(4)));

__device__ __forceinline__ unsigned short f2bf_rne(float f) {
  unsigned int u = __float_as_uint(f);
  u += 0x7FFFu + ((u >> 16) & 1u);
  return (unsigned short)(u >> 16);
}
__device__ __forceinline__ float bf2f(unsigned short h) {
  return __uint_as_float(((unsigned int)h) << 16);
}

__device__ __forceinline__ void async_load16(const void* g, void* l) {
  __builtin_amdgcn_global_load_lds(
      (const __attribute__((address_space(1))) void*)g,
      (__attribute__((address_space(3))) void*)l,
      16, 0, 0);
}

// ----------------------------------------------------------------------------
// split fp32 -> bf16 hi/lo (lo==nullptr: plain convert). One float4 per thread.
// ----------------------------------------------------------------------------
__global__ __launch_bounds__(256) void split_kernel(
    const float* __restrict__ x, unsigned short* __restrict__ hi,
    unsigned short* __restrict__ lo, long n4)
{
  long i = (long)blockIdx.x * 256 + threadIdx.x;
  if (i >= n4) return;
  float4 v = ((const float4*)x)[i];
  ushort4 h;
  h.x = f2bf_rne(v.x); h.y = f2bf_rne(v.y);
  h.z = f2bf_rne(v.z); h.w = f2bf_rne(v.w);
  ((ushort4*)hi)[i] = h;
  if (lo) {
    ushort4 l;
    l.x = f2bf_rne(v.x - bf2f(h.x));
    l.y = f2bf_rne(v.y - bf2f(h.y));
    l.z = f2bf_rne(v.z - bf2f(h.z));
    l.w = f2bf_rne(v.w - bf2f(h.w));
    ((ushort4*)lo)[i] = l;
  }
}

// ----------------------------------------------------------------------------
// ct[b][d][k] = bf16(c[k][b][d]).  64x64 tiles via LDS.
// grid: (k_tiles=32, d_tiles=16, b=16)
// ----------------------------------------------------------------------------
__global__ __launch_bounds__(256) void transpose_kernel(
    const float* __restrict__ c, unsigned short* __restrict__ ct)
{
  __shared__ unsigned short t[64 * 68];
  int k0 = blockIdx.x * 64;
  int d0 = blockIdx.y * 64;
  int b  = blockIdx.z;
  int tid = threadIdx.x;
  #pragma unroll
  for (int p4 = 0; p4 < 4; ++p4) {
    int idx = p4 * 256 + tid;
    int kr = idx >> 4;
    int dc = (idx & 15) * 4;
    float4 v = *(const float4*)&c[(long)(k0 + kr) * 16384 + (long)b * 1024 + d0 + dc];
    ushort4 h;
    h.x = f2bf_rne(v.x); h.y = f2bf_rne(v.y);
    h.z = f2bf_rne(v.z); h.w = f2bf_rne(v.w);
    *(ushort4*)&t[kr * 68 + dc] = h;
  }
  __syncthreads();
  #pragma unroll
  for (int p4 = 0; p4 < 4; ++p4) {
    int idx = p4 * 256 + tid;
    int dr = idx >> 4;
    int kc = (idx & 15) * 4;
    ushort4 o;
    o.x = t[(kc + 0) * 68 + dr];
    o.y = t[(kc + 1) * 68 + dr];
    o.z = t[(kc + 2) * 68 + dr];
    o.w = t[(kc + 3) * 68 + dr];
    *(ushort4*)&ct[(long)b * 2097152 + (long)(d0 + dr) * 2048 + k0 + kc] = o;
  }
}

// ----------------------------------------------------------------------------
// row softmax over 2048 fp32 (in place) + bf16 copy for the ctx GEMM.
// one 256-thread block per row.
// ----------------------------------------------------------------------------
__global__ __launch_bounds__(256) void softmax_kernel(
    float* __restrict__ S, unsigned short* __restrict__ P)
{
  __shared__ float sred[8];
  long row = blockIdx.x;
  float* p = S + row * 2048;
  int tid = threadIdx.x;
  int lane = tid & 63, w = tid >> 6;
  float4 v0 = ((float4*)p)[tid];
  float4 v1 = ((float4*)p)[tid + 256];
  float m = fmaxf(fmaxf(fmaxf(v0.x, v0.y), fmaxf(v0.z, v0.w)),
                  fmaxf(fmaxf(v1.x, v1.y), fmaxf(v1.z, v1.w)));
  #pragma unroll
  for (int off = 32; off; off >>= 1) m = fmaxf(m, __shfl_xor(m, off));
  if (lane == 0) sred[w] = m;
  __syncthreads();
  m = fmaxf(fmaxf(sred[0], sred[1]), fmaxf(sred[2], sred[3]));
  v0.x = __expf(v0.x - m); v0.y = __expf(v0.y - m);
  v0.z = __expf(v0.z - m); v0.w = __expf(v0.w - m);
  v1.x = __expf(v1.x - m); v1.y = __expf(v1.y - m);
  v1.z = __expf(v1.z - m); v1.w = __expf(v1.w - m);
  float s = v0.x + v0.y + v0.z + v0.w + v1.x + v1.y + v1.z + v1.w;
  #pragma unroll
  for (int off = 32; off; off >>= 1) s += __shfl_xor(s, off);
  if (lane == 0) sred[4 + w] = s;
  __syncthreads();
  s = sred[4] + sred[5] + sred[6] + sred[7];
  float inv = 1.0f / s;
  v0.x *= inv; v0.y *= inv; v0.z *= inv; v0.w *= inv;
  v1.x *= inv; v1.y *= inv; v1.z *= inv; v1.w *= inv;
  ((float4*)p)[tid] = v0;
  ((float4*)p)[tid + 256] = v1;
  unsigned short* pp = P + row * 2048;
  ushort4 b0, b1;
  b0.x = f2bf_rne(v0.x); b0.y = f2bf_rne(v0.y);
  b0.z = f2bf_rne(v0.z); b0.w = f2bf_rne(v0.w);
  b1.x = f2bf_rne(v1.x); b1.y = f2bf_rne(v1.y);
  b1.z = f2bf_rne(v1.z); b1.w = f2bf_rne(v1.w);
  ((ushort4*)pp)[tid] = b0;
  ((ushort4*)pp)[tid + 256] = b1;
}

// ----------------------------------------------------------------------------
// Pipelined TN GEMM: C[bz][m][n] = sum_k A[bz][m][k] * B[bz][n][k]
// 256x256 block tile, 512 threads = 8 waves (2M x 4N), per-wave 128x64.
// BK=32 K-tiles in a ring of 4 LDS buffers; iteration t stages tile t+3,
// waits vmcnt(8) (retire tile t only), one barrier per K-step.
// SPLIT=1: virtual K = 3*K; tile vt -> (k = vt/3*32, term = vt%3) with
//          sources (Ah,Bh),(Ah,Bl),(Al,Bh)  [3-term bf16 emulation].
// LDS slot swizzle (proven 0-conflict): slot = row*4 + (kb ^ ((row>>1)&3)).
// XCD swizzle: flat%8 = XCD; XCD owns an SM x SN sub-grid of 256-tiles
// (requires gridm = GM*SM, gridn = (8/GM)*SN); n varies fastest.
// MODE 0: fp32 C            MODE 1: bf16 C
// MODE 2: fp32 tanh, row m=(b*1024+q) remapped to out[(q*16+b)*1024+n]
// MODE 3: split write: P1/P2 = hi/lo at [m*1024+n]; Cp = cat bf16 at
//         [( (m&15)*1024 + (m>>4) )*2048 + 1024 + n]   (m = q*16+b)
// ----------------------------------------------------------------------------
template<int SPLIT, int MODE>
__global__ __launch_bounds__(512, 2) void gemm_kernel(
    const unsigned short* __restrict__ Ah, const unsigned short* __restrict__ Al,
    long sAb, long ldA,
    const unsigned short* __restrict__ Bh, const unsigned short* __restrict__ Bl,
    long sBb, long ldB,
    void* __restrict__ Cp, long sCb, long ldC,
    unsigned short* __restrict__ P1, unsigned short* __restrict__ P2,
    int K, int SM, int SN, int GM)
{
  // ring of 4 K-tile buffers: A_r at r*8192 shorts (16KB), B_r at 32768+r*8192
  __shared__ __align__(16) unsigned short lds[65536];   // 128 KiB

  const int tid  = threadIdx.x;
  const int lane = tid & 63;
  const int w    = tid >> 6;      // 0..7
  const int wm   = w >> 2;        // 0..1
  const int wn   = w & 3;         // 0..3
  const int bz   = blockIdx.z;

  // XCD-aware remap (flat%8 assumed = XCD; locality-only heuristic)
  const int flat = blockIdx.x + gridDim.x * blockIdx.y;
  const int sub  = flat & 7;
  const int g    = flat >> 3;
  const long mt  = (long)(sub % GM) * SM + (g / SN);
  const long nt  = (long)(sub / GM) * SN + (g % SN);
  const long m0  = mt * 256;
  const long n0  = nt * 256;

  const unsigned short* a0 = Ah + bz * sAb + m0 * ldA;
  const unsigned short* a1 = SPLIT ? (Al + bz * sAb + m0 * ldA) : a0;
  const unsigned short* b0 = Bh + bz * sBb + n0 * ldB;
  const unsigned short* b1 = SPLIT ? (Bl + bz * sBb + n0 * ldB) : b0;

  // Staging geometry: per tile-operand 1024 16B-slots; 512 threads x 2 issues.
  // slot_linear s -> row = s>>2, stored k-slot kb = (s&3) ^ ((row>>1)&3);
  // global source is pre-swizzled so LDS dest stays linear (rule 21).
  const int s0r = tid >> 2,        s1r = (512 + tid) >> 2;
  const int s0k = (tid & 3) ^ ((s0r >> 1) & 3);
  const int s1k = ((512 + tid) & 3) ^ ((s1r >> 1) & 3);
  const long offA0 = (long)s0r * ldA + s0k * 8;
  const long offA1 = (long)s1r * ldA + s1k * 8;
  const long offB0 = (long)s0r * ldB + s0k * 8;
  const long offB1 = (long)s1r * ldB + s1k * 8;
  const int d0 = w * 512;          // wave-uniform LDS dest (shorts), issue 0
  const int d1 = 4096 + w * 512;   // issue 1

  const int nkt = SPLIT ? 3 * (K / 32) : (K / 32);

  floatx4 acc[8][4] = {};

  auto stage = [&](int vt2) {
    const int slot = vt2 & 3;
    const unsigned short* As;
    const unsigned short* Bs;
    long ks;
    if (SPLIT) {
      int term = vt2 % 3;                 // 0:hh 1:hl 2:lh (same k back-to-back)
      ks = (long)(vt2 / 3) * 32;
      As = (term < 2) ? a0 : a1;
      Bs = (term == 1) ? b1 : b0;
    } else {
      As = a0; Bs = b0; ks = (long)vt2 * 32;
    }
    const int ab = slot * 8192;
    const int bb = 32768 + slot * 8192;
    async_load16(As + offA0 + ks, &lds[ab + d0]);
    async_load16(As + offA1 + ks, &lds[ab + d1]);
    async_load16(Bs + offB0 + ks, &lds[bb + d0]);
    async_load16(Bs + offB1 + ks, &lds[bb + d1]);
  };

  // prologue: 3 tiles in flight (12 vmcnt ops/thread)
  stage(0); stage(1); stage(2);

  for (int vt = 0; vt < nkt; ++vt) {
    // retire exactly tile vt (4 loads); keep up to 2 newer tiles in flight
    const int ahead = nkt - 1 - vt;
    if (ahead >= 2)      asm volatile("s_waitcnt vmcnt(8)" ::: "memory");
    else if (ahead == 1) asm volatile("s_waitcnt vmcnt(4)" ::: "memory");
    else                 asm volatile("s_waitcnt vmcnt(0)" ::: "memory");
    __builtin_amdgcn_s_barrier();
    __builtin_amdgcn_sched_barrier(0);

    if (vt + 3 < nkt) stage(vt + 3);     // overwrites slot (vt-1)&3: reads done
    __builtin_amdgcn_sched_barrier(0);

    const unsigned short* At = &lds[(vt & 3) * 8192];
    const unsigned short* Bt = &lds[32768 + (vt & 3) * 8192];

    bf16x8 fb[4];
    #pragma unroll
    for (int j = 0; j < 4; ++j) {
      int r    = wn * 64 + j * 16 + (lane & 15);
      int slot = r * 4 + ((lane >> 4) ^ ((r >> 1) & 3));
      fb[j] = *(const bf16x8*)&Bt[slot * 8];
    }
    __builtin_amdgcn_s_setprio(1);
    #pragma unroll
    for (int i = 0; i < 8; ++i) {
      int r    = wm * 128 + i * 16 + (lane & 15);
      int slot = r * 4 + ((lane >> 4) ^ ((r >> 1) & 3));
      bf16x8 fa = *(const bf16x8*)&At[slot * 8];
      #pragma unroll
      for (int j = 0; j < 4; ++j)
        acc[i][j] = __builtin_amdgcn_mfma_f32_16x16x32_bf16(fa, fb[j], acc[i][j], 0, 0, 0);
    }
    __builtin_amdgcn_s_setprio(0);
  }

  // epilogue: C/D layout col=lane&15, row=(lane>>4)*4+reg  [m89-verified]
  #pragma unroll
  for (int i = 0; i < 8; ++i) {
    #pragma unroll
    for (int j = 0; j < 4; ++j) {
      #pragma unroll
      for (int t = 0; t < 4; ++t) {
        long rg = m0 + wm * 128 + i * 16 + (lane >> 4) * 4 + t;
        long cg = n0 + wn * 64 + j * 16 + (lane & 15);
        float v = acc[i][j][t];
        if (MODE == 0) {
          ((float*)Cp)[bz * sCb + rg * ldC + cg] = v;
        } else if (MODE == 1) {
          ((unsigned short*)Cp)[bz * sCb + rg * ldC + cg] = f2bf_rne(v);
        } else if (MODE == 2) {
          long qq = rg & 1023, bb = rg >> 10;
          ((float*)Cp)[(qq * 16 + bb) * 1024 + cg] = tanhf(v);
        } else {
          unsigned short hv = f2bf_rne(v);
          unsigned short lv = f2bf_rne(v - bf2f(hv));
          P1[rg * 1024 + cg] = hv;
          P2[rg * 1024 + cg] = lv;
          long bb = rg & 15, qq = rg >> 4;
          ((unsigned short*)Cp)[(bb * 1024 + qq) * 2048 + 1024 + cg] = hv;
        }
      }
    }
  }
}

// ============================================================================
extern "C" void kernel_launch(void* const* d_in, const int* in_sizes, int n_in,
                              void* d_out, int out_size, void* d_ws, size_t ws_size,
                              hipStream_t stream)
{
  const float* q    = (const float*)d_in[0];   // [1024,16,1024]
  const float* c    = (const float*)d_in[1];   // [2048,16,1024]
  const float* Win  = (const float*)d_in[2];   // [1024,1024]
  const float* Wout = (const float*)d_in[3];   // [1024,2048]

  char* ws = (char*)d_ws;
  const size_t MB = 1024u * 1024u;

  unsigned short* qh  = (unsigned short*)(ws);             // region A phase 1
  unsigned short* ch  = (unsigned short*)(ws);             // region A phase 2
  unsigned short* pb  = (unsigned short*)(ws);             // region A phase 3
  unsigned short* qbh = (unsigned short*)(ws + 64 * MB);   // region B phase 1
  unsigned short* qbl = (unsigned short*)(ws + 96 * MB);
  unsigned short* ct  = (unsigned short*)(ws + 64 * MB);   // region B phase 2
  unsigned short* cat = (unsigned short*)(ws + 128 * MB);  // region C
  unsigned short* Wh  = (unsigned short*)(ws + 192 * MB);
  unsigned short* Wl  = (unsigned short*)(ws + 194 * MB);
  unsigned short* Wo  = (unsigned short*)(ws + 196 * MB);

  unsigned short* ql  = (unsigned short*)d_out;            // out-region scratch
  unsigned short* cl  = (unsigned short*)d_out;            // out-region scratch
  float* out0  = (float*)d_out;                            // [1024,16,1024]
  float* score = (float*)d_out + 16777216;                 // [16,1024,2048]

  // phase 1: splits/converts needed by G1
  split_kernel<<<16384, 256, 0, stream>>>(q,    qh, ql,      4194304L);
  split_kernel<<<1024,  256, 0, stream>>>(Win,  Wh, Wl,      262144L);
  split_kernel<<<2048,  256, 0, stream>>>(Wout, Wo, nullptr, 524288L);

  // G1: qb = q @ Win^T  (split), M=16384 (rows q*16+b), N=1024, K=1024
  // tiles 64m x 4n; XCD sub-grid 8m x 4n
  gemm_kernel<1, 3><<<dim3(32, 8, 1), 512, 0, stream>>>(
      qh, ql, 0L, 1024L, Wh, Wl, 0L, 1024L,
      (void*)cat, 0L, 0L, qbh, qbl, 1024, 8, 4, 8);

  // phase 2: split c (q_hi/q_lo now dead)
  split_kernel<<<32768, 256, 0, stream>>>(c, ch, cl, 8388608L);

  // G2: logits[b][q][k] = qb[b,q,:] . c[k,b,:]  (split)
  // tiles 4m x 8n per batch; XCD sub-grid 2m x 2n (4MB hi+lo = one XCD L2)
  gemm_kernel<1, 0><<<dim3(4, 8, 16), 512, 0, stream>>>(
      qbh, qbl, 1024L, 16384L, ch, cl, 1024L, 16384L,
      (void*)score, 2097152L, 2048L, nullptr, nullptr, 1024, 2, 2, 2);

  // phase 3 (qb/c_hi/c_lo dead): transpose c, softmax in place
  transpose_kernel<<<dim3(32, 16, 16), 256, 0, stream>>>(c, ct);
  softmax_kernel<<<16384, 256, 0, stream>>>(score, pb);

  // G4: ctx[b][q][d] = P[b,q,:] . ct[b,d,:]  -> cat[...,0:1024] bf16
  // tiles 4m x 4n per batch; XCD sub-grid 1m x 2n
  gemm_kernel<0, 1><<<dim3(4, 4, 16), 512, 0, stream>>>(
      pb, nullptr, 2097152L, 2048L, ct, nullptr, 2097152L, 2048L,
      (void*)cat, 2097152L, 2048L, nullptr, nullptr, 2048, 1, 2, 4);

  // G5: out[(q*16+b)*1024+d] = tanh(cat[b*1024+q,:] . Wout[d,:])
  // tiles 64m x 4n; XCD sub-grid 8m x 4n
  gemm_kernel<0, 2><<<dim3(32, 8, 1), 512, 0, stream>>>(
      cat, nullptr, 0L, 2048L, Wo, nullptr, 0L, 2048L,
      (void*)out0, 0L, 0L, nullptr, nullptr, 2048, 8, 4, 8);

  (void)in_sizes; (void)n_in; (void)out_size; (void)ws_size;
}

// Round 2
// 908.381 us; speedup vs baseline: 1.0622x; 1.0231x over previous
//
#include <hip/hip_runtime.h>
#include <hip/hip_bf16.h>
#include <stdint.h>

// ============================================================================
// Attn_50233937494279: qb=q@Win^T; S=softmax(qb@c^T); ctx=S@c;
//                      out=tanh([ctx|qb]@Wout^T); returns (out[q,b,d], S[b,q,k])
//
// R3 -> R4: SPLIT=1 GEMM path restructured from "3 virtual tiles per k"
// (staged 6 operand-tiles/k, 3 barriers/96 MFMA, 36 ds_reads) to unique-entry
// two-phase pipeline:
//   per k: stage e0={Ah,Bh} and e1={Al,Bl} (4 unique tiles, 8 loads/thread);
//   phase 1 = hh (32 MFMA, needs e0 only); phase 2 = hl+lh (64 MFMA, needs
//   e1; fbh kept live in VGPRs). Waits: vmcnt(4) at top (retire e0(k)),
//   vmcnt(8) mid (retire e1(k), keep e(k+1,*)). 2 barriers / 96 MFMA.
//   Ring-4 of 32KB slots: iter k reads slots {2k,2k+1}&3, stages {2k+2,2k+3}&3.
// SPLIT=0 path (G4/G5) unchanged: ring-4 BK=32 depth-3, vmcnt(8/4/0).
//
// Precision: GEMM1/GEMM2 (pre-softmax) 3-term split-bf16; G4/G5 plain bf16.
// Workspace layout (200 MB), region reuse across stream-ordered phases:
//   A @ 0      (64MB): q_hi -> c_hi (after G1) -> p_bf16 (after G2)
//   B @ 64MB   (64MB): qb_hi+qb_lo -> ct (c transposed, after G2)
//   C @ 128MB  (64MB): cat = [ctx | qb] bf16
//   W @ 192MB  ( 8MB): Win_hi, Win_lo, Wout_bf16
//   d_out out-region (64MB, unused until G5): q_lo -> c_lo scratch
// ============================================================================

typedef __bf16 bf16x8 __attribute__((ext_vector_type(8)));
typedef float floatx4 __attribute__((ext_vector_type(4)));

__device__ __forceinline__ unsigned short f2bf_rne(float f) {
  unsigned int u = __float_as_uint(f);
  u += 0x7FFFu + ((u >> 16) & 1u);
  return (unsigned short)(u >> 16);
}
__device__ __forceinline__ float bf2f(unsigned short h) {
  return __uint_as_float(((unsigned int)h) << 16);
}

__device__ __forceinline__ void async_load16(const void* g, void* l) {
  __builtin_amdgcn_global_load_lds(
      (const __attribute__((address_space(1))) void*)g,
      (__attribute__((address_space(3))) void*)l,
      16, 0, 0);
}

// ----------------------------------------------------------------------------
// split fp32 -> bf16 hi/lo (lo==nullptr: plain convert). One float4 per thread.
// ----------------------------------------------------------------------------
__global__ __launch_bounds__(256) void split_kernel(
    const float* __restrict__ x, unsigned short* __restrict__ hi,
    unsigned short* __restrict__ lo, long n4)
{
  long i = (long)blockIdx.x * 256 + threadIdx.x;
  if (i >= n4) return;
  float4 v = ((const float4*)x)[i];
  ushort4 h;
  h.x = f2bf_rne(v.x); h.y = f2bf_rne(v.y);
  h.z = f2bf_rne(v.z); h.w = f2bf_rne(v.w);
  ((ushort4*)hi)[i] = h;
  if (lo) {
    ushort4 l;
    l.x = f2bf_rne(v.x - bf2f(h.x));
    l.y = f2bf_rne(v.y - bf2f(h.y));
    l.z = f2bf_rne(v.z - bf2f(h.z));
    l.w = f2bf_rne(v.w - bf2f(h.w));
    ((ushort4*)lo)[i] = l;
  }
}

// ----------------------------------------------------------------------------
// ct[b][d][k] = bf16(c[k][b][d]).  64x64 tiles via LDS.
// grid: (k_tiles=32, d_tiles=16, b=16)
// ----------------------------------------------------------------------------
__global__ __launch_bounds__(256) void transpose_kernel(
    const float* __restrict__ c, unsigned short* __restrict__ ct)
{
  __shared__ unsigned short t[64 * 68];
  int k0 = blockIdx.x * 64;
  int d0 = blockIdx.y * 64;
  int b  = blockIdx.z;
  int tid = threadIdx.x;
  #pragma unroll
  for (int p4 = 0; p4 < 4; ++p4) {
    int idx = p4 * 256 + tid;
    int kr = idx >> 4;
    int dc = (idx & 15) * 4;
    float4 v = *(const float4*)&c[(long)(k0 + kr) * 16384 + (long)b * 1024 + d0 + dc];
    ushort4 h;
    h.x = f2bf_rne(v.x); h.y = f2bf_rne(v.y);
    h.z = f2bf_rne(v.z); h.w = f2bf_rne(v.w);
    *(ushort4*)&t[kr * 68 + dc] = h;
  }
  __syncthreads();
  #pragma unroll
  for (int p4 = 0; p4 < 4; ++p4) {
    int idx = p4 * 256 + tid;
    int dr = idx >> 4;
    int kc = (idx & 15) * 4;
    ushort4 o;
    o.x = t[(kc + 0) * 68 + dr];
    o.y = t[(kc + 1) * 68 + dr];
    o.z = t[(kc + 2) * 68 + dr];
    o.w = t[(kc + 3) * 68 + dr];
    *(ushort4*)&ct[(long)b * 2097152 + (long)(d0 + dr) * 2048 + k0 + kc] = o;
  }
}

// ----------------------------------------------------------------------------
// row softmax over 2048 fp32 (in place) + bf16 copy for the ctx GEMM.
// one 256-thread block per row.
// ----------------------------------------------------------------------------
__global__ __launch_bounds__(256) void softmax_kernel(
    float* __restrict__ S, unsigned short* __restrict__ P)
{
  __shared__ float sred[8];
  long row = blockIdx.x;
  float* p = S + row * 2048;
  int tid = threadIdx.x;
  int lane = tid & 63, w = tid >> 6;
  float4 v0 = ((float4*)p)[tid];
  float4 v1 = ((float4*)p)[tid + 256];
  float m = fmaxf(fmaxf(fmaxf(v0.x, v0.y), fmaxf(v0.z, v0.w)),
                  fmaxf(fmaxf(v1.x, v1.y), fmaxf(v1.z, v1.w)));
  #pragma unroll
  for (int off = 32; off; off >>= 1) m = fmaxf(m, __shfl_xor(m, off));
  if (lane == 0) sred[w] = m;
  __syncthreads();
  m = fmaxf(fmaxf(sred[0], sred[1]), fmaxf(sred[2], sred[3]));
  v0.x = __expf(v0.x - m); v0.y = __expf(v0.y - m);
  v0.z = __expf(v0.z - m); v0.w = __expf(v0.w - m);
  v1.x = __expf(v1.x - m); v1.y = __expf(v1.y - m);
  v1.z = __expf(v1.z - m); v1.w = __expf(v1.w - m);
  float s = v0.x + v0.y + v0.z + v0.w + v1.x + v1.y + v1.z + v1.w;
  #pragma unroll
  for (int off = 32; off; off >>= 1) s += __shfl_xor(s, off);
  if (lane == 0) sred[4 + w] = s;
  __syncthreads();
  s = sred[4] + sred[5] + sred[6] + sred[7];
  float inv = 1.0f / s;
  v0.x *= inv; v0.y *= inv; v0.z *= inv; v0.w *= inv;
  v1.x *= inv; v1.y *= inv; v1.z *= inv; v1.w *= inv;
  ((float4*)p)[tid] = v0;
  ((float4*)p)[tid + 256] = v1;
  unsigned short* pp = P + row * 2048;
  ushort4 b0, b1;
  b0.x = f2bf_rne(v0.x); b0.y = f2bf_rne(v0.y);
  b0.z = f2bf_rne(v0.z); b0.w = f2bf_rne(v0.w);
  b1.x = f2bf_rne(v1.x); b1.y = f2bf_rne(v1.y);
  b1.z = f2bf_rne(v1.z); b1.w = f2bf_rne(v1.w);
  ((ushort4*)pp)[tid] = b0;
  ((ushort4*)pp)[tid + 256] = b1;
}

// ----------------------------------------------------------------------------
// Pipelined TN GEMM: C[bz][m][n] = sum_k A[bz][m][k] * B[bz][n][k]
// 256x256 block tile, 512 threads = 8 waves (2M x 4N), per-wave 128x64.
// LDS ring of 4 slots (slot = 16KB A-tile + 16KB B-tile), counted vmcnt,
// one/two barriers per K-step, never vmcnt(0) in steady state.
// SPLIT=1: per k stage e0={Ah,Bh}@slot(2k)&3, e1={Al,Bl}@slot(2k+1)&3;
//          phase1 = hh (32 MFMA), phase2 = hl+lh (64 MFMA, fbh live).
// SPLIT=0: plain bf16, ring-4 BK=32 depth-3 prefetch, vmcnt(8/4/0).
// LDS slot swizzle (proven 0-conflict): slot = row*4 + (kb ^ ((row>>1)&3)).
// XCD swizzle: flat%8 = XCD; XCD owns an SM x SN sub-grid of 256-tiles
// (requires gridm = GM*SM, gridn = (8/GM)*SN); n varies fastest.
// MODE 0: fp32 C            MODE 1: bf16 C
// MODE 2: fp32 tanh, row m=(b*1024+q) remapped to out[(q*16+b)*1024+n]
// MODE 3: split write: P1/P2 = hi/lo at [m*1024+n]; Cp = cat bf16 at
//         [( (m&15)*1024 + (m>>4) )*2048 + 1024 + n]   (m = q*16+b)
// ----------------------------------------------------------------------------
template<int SPLIT, int MODE>
__global__ __launch_bounds__(512, 2) void gemm_kernel(
    const unsigned short* __restrict__ Ah, const unsigned short* __restrict__ Al,
    long sAb, long ldA,
    const unsigned short* __restrict__ Bh, const unsigned short* __restrict__ Bl,
    long sBb, long ldB,
    void* __restrict__ Cp, long sCb, long ldC,
    unsigned short* __restrict__ P1, unsigned short* __restrict__ P2,
    int K, int SM, int SN, int GM)
{
  // ring of 4 slots: A_r at r*8192 shorts (16KB), B_r at 32768+r*8192
  __shared__ __align__(16) unsigned short lds[65536];   // 128 KiB

  const int tid  = threadIdx.x;
  const int lane = tid & 63;
  const int w    = tid >> 6;      // 0..7
  const int wm   = w >> 2;        // 0..1
  const int wn   = w & 3;         // 0..3
  const int bz   = blockIdx.z;

  // XCD-aware remap (flat%8 assumed = XCD; locality-only heuristic)
  const int flat = blockIdx.x + gridDim.x * blockIdx.y;
  const int sub  = flat & 7;
  const int g    = flat >> 3;
  const long mt  = (long)(sub % GM) * SM + (g / SN);
  const long nt  = (long)(sub / GM) * SN + (g % SN);
  const long m0  = mt * 256;
  const long n0  = nt * 256;

  const unsigned short* a0 = Ah + bz * sAb + m0 * ldA;
  const unsigned short* a1 = SPLIT ? (Al + bz * sAb + m0 * ldA) : a0;
  const unsigned short* b0 = Bh + bz * sBb + n0 * ldB;
  const unsigned short* b1 = SPLIT ? (Bl + bz * sBb + n0 * ldB) : b0;

  // Staging geometry: per tile-operand 1024 16B-slots; 512 threads x 2 issues.
  // slot_linear s -> row = s>>2, stored k-slot kb = (s&3) ^ ((row>>1)&3);
  // global source is pre-swizzled so LDS dest stays linear (rule 21).
  const int s0r = tid >> 2,        s1r = (512 + tid) >> 2;
  const int s0k = (tid & 3) ^ ((s0r >> 1) & 3);
  const int s1k = ((512 + tid) & 3) ^ ((s1r >> 1) & 3);
  const long offA0 = (long)s0r * ldA + s0k * 8;
  const long offA1 = (long)s1r * ldA + s1k * 8;
  const long offB0 = (long)s0r * ldB + s0k * 8;
  const long offB1 = (long)s1r * ldB + s1k * 8;
  const int d0 = w * 512;          // wave-uniform LDS dest (shorts), issue 0
  const int d1 = 4096 + w * 512;   // issue 1

  floatx4 acc[8][4] = {};

  if constexpr (SPLIT) {
    // ---------------- two-phase unique-entry split pipeline ----------------
    const int nk = K / 32;

    auto stageE = [&](int k, int h) {    // h=0: {Ah,Bh}; h=1: {Al,Bl}
      const int slot = (2 * k + h) & 3;
      const unsigned short* As = h ? a1 : a0;
      const unsigned short* Bs = h ? b1 : b0;
      const long ks = (long)k * 32;
      const int ab = slot * 8192;
      const int bb = 32768 + slot * 8192;
      async_load16(As + offA0 + ks, &lds[ab + d0]);
      async_load16(As + offA1 + ks, &lds[ab + d1]);
      async_load16(Bs + offB0 + ks, &lds[bb + d0]);
      async_load16(Bs + offB1 + ks, &lds[bb + d1]);
    };

    stageE(0, 0); stageE(0, 1);          // prologue: 8 loads in flight

    for (int k = 0; k < nk; ++k) {
      // retire e0(k)={Ah,Bh}; keep e1(k) in flight
      asm volatile("s_waitcnt vmcnt(4)" ::: "memory");
      __builtin_amdgcn_s_barrier();
      __builtin_amdgcn_sched_barrier(0);

      if (k + 1 < nk) { stageE(k + 1, 0); stageE(k + 1, 1); }  // +8 in flight
      __builtin_amdgcn_sched_barrier(0);

      const unsigned short* Ah_t = &lds[((2 * k) & 3) * 8192];
      const unsigned short* Bh_t = &lds[32768 + ((2 * k) & 3) * 8192];
      const unsigned short* Al_t = &lds[((2 * k + 1) & 3) * 8192];
      const unsigned short* Bl_t = &lds[32768 + ((2 * k + 1) & 3) * 8192];

      bf16x8 fbh[4];
      #pragma unroll
      for (int j = 0; j < 4; ++j) {
        int r    = wn * 64 + j * 16 + (lane & 15);
        int slot = r * 4 + ((lane >> 4) ^ ((r >> 1) & 3));
        fbh[j] = *(const bf16x8*)&Bh_t[slot * 8];
      }
      // phase 1: hh
      __builtin_amdgcn_s_setprio(1);
      #pragma unroll
      for (int i = 0; i < 8; ++i) {
        int r    = wm * 128 + i * 16 + (lane & 15);
        int slot = r * 4 + ((lane >> 4) ^ ((r >> 1) & 3));
        bf16x8 fah = *(const bf16x8*)&Ah_t[slot * 8];
        #pragma unroll
        for (int j = 0; j < 4; ++j)
          acc[i][j] = __builtin_amdgcn_mfma_f32_16x16x32_bf16(fah, fbh[j], acc[i][j], 0, 0, 0);
      }
      __builtin_amdgcn_s_setprio(0);

      // retire e1(k)={Al,Bl}; keep e(k+1,*) in flight
      if (k + 1 < nk) asm volatile("s_waitcnt vmcnt(8)" ::: "memory");
      else            asm volatile("s_waitcnt vmcnt(0)" ::: "memory");
      __builtin_amdgcn_s_barrier();
      __builtin_amdgcn_sched_barrier(0);

      bf16x8 fbl[4];
      #pragma unroll
      for (int j = 0; j < 4; ++j) {
        int r    = wn * 64 + j * 16 + (lane & 15);
        int slot = r * 4 + ((lane >> 4) ^ ((r >> 1) & 3));
        fbl[j] = *(const bf16x8*)&Bl_t[slot * 8];
      }
      // phase 2: hl (Ah x Bl) then lh (Al x Bh, fbh still live)
      __builtin_amdgcn_s_setprio(1);
      #pragma unroll
      for (int i = 0; i < 8; ++i) {
        int r    = wm * 128 + i * 16 + (lane & 15);
        int slot = r * 4 + ((lane >> 4) ^ ((r >> 1) & 3));
        bf16x8 fah = *(const bf16x8*)&Ah_t[slot * 8];
        #pragma unroll
        for (int j = 0; j < 4; ++j)
          acc[i][j] = __builtin_amdgcn_mfma_f32_16x16x32_bf16(fah, fbl[j], acc[i][j], 0, 0, 0);
      }
      #pragma unroll
      for (int i = 0; i < 8; ++i) {
        int r    = wm * 128 + i * 16 + (lane & 15);
        int slot = r * 4 + ((lane >> 4) ^ ((r >> 1) & 3));
        bf16x8 fal = *(const bf16x8*)&Al_t[slot * 8];
        #pragma unroll
        for (int j = 0; j < 4; ++j)
          acc[i][j] = __builtin_amdgcn_mfma_f32_16x16x32_bf16(fal, fbh[j], acc[i][j], 0, 0, 0);
      }
      __builtin_amdgcn_s_setprio(0);
    }
  } else {
    // ---------------- plain bf16 ring-4 depth-3 pipeline (unchanged) ------
    const int nkt = K / 32;

    auto stage = [&](int vt2) {
      const int slot = vt2 & 3;
      const long ks = (long)vt2 * 32;
      const int ab = slot * 8192;
      const int bb = 32768 + slot * 8192;
      async_load16(a0 + offA0 + ks, &lds[ab + d0]);
      async_load16(a0 + offA1 + ks, &lds[ab + d1]);
      async_load16(b0 + offB0 + ks, &lds[bb + d0]);
      async_load16(b0 + offB1 + ks, &lds[bb + d1]);
    };

    stage(0); stage(1); stage(2);

    for (int vt = 0; vt < nkt; ++vt) {
      const int ahead = nkt - 1 - vt;
      if (ahead >= 2)      asm volatile("s_waitcnt vmcnt(8)" ::: "memory");
      else if (ahead == 1) asm volatile("s_waitcnt vmcnt(4)" ::: "memory");
      else                 asm volatile("s_waitcnt vmcnt(0)" ::: "memory");
      __builtin_amdgcn_s_barrier();
      __builtin_amdgcn_sched_barrier(0);

      if (vt + 3 < nkt) stage(vt + 3);
      __builtin_amdgcn_sched_barrier(0);

      const unsigned short* At = &lds[(vt & 3) * 8192];
      const unsigned short* Bt = &lds[32768 + (vt & 3) * 8192];

      bf16x8 fb[4];
      #pragma unroll
      for (int j = 0; j < 4; ++j) {
        int r    = wn * 64 + j * 16 + (lane & 15);
        int slot = r * 4 + ((lane >> 4) ^ ((r >> 1) & 3));
        fb[j] = *(const bf16x8*)&Bt[slot * 8];
      }
      __builtin_amdgcn_s_setprio(1);
      #pragma unroll
      for (int i = 0; i < 8; ++i) {
        int r    = wm * 128 + i * 16 + (lane & 15);
        int slot = r * 4 + ((lane >> 4) ^ ((r >> 1) & 3));
        bf16x8 fa = *(const bf16x8*)&At[slot * 8];
        #pragma unroll
        for (int j = 0; j < 4; ++j)
          acc[i][j] = __builtin_amdgcn_mfma_f32_16x16x32_bf16(fa, fb[j], acc[i][j], 0, 0, 0);
      }
      __builtin_amdgcn_s_setprio(0);
    }
  }

  // epilogue: C/D layout col=lane&15, row=(lane>>4)*4+reg  [m89-verified]
  #pragma unroll
  for (int i = 0; i < 8; ++i) {
    #pragma unroll
    for (int j = 0; j < 4; ++j) {
      #pragma unroll
      for (int t = 0; t < 4; ++t) {
        long rg = m0 + wm * 128 + i * 16 + (lane >> 4) * 4 + t;
        long cg = n0 + wn * 64 + j * 16 + (lane & 15);
        float v = acc[i][j][t];
        if (MODE == 0) {
          ((float*)Cp)[bz * sCb + rg * ldC + cg] = v;
        } else if (MODE == 1) {
          ((unsigned short*)Cp)[bz * sCb + rg * ldC + cg] = f2bf_rne(v);
        } else if (MODE == 2) {
          long qq = rg & 1023, bb = rg >> 10;
          ((float*)Cp)[(qq * 16 + bb) * 1024 + cg] = tanhf(v);
        } else {
          unsigned short hv = f2bf_rne(v);
          unsigned short lv = f2bf_rne(v - bf2f(hv));
          P1[rg * 1024 + cg] = hv;
          P2[rg * 1024 + cg] = lv;
          long bb = rg & 15, qq = rg >> 4;
          ((unsigned short*)Cp)[(bb * 1024 + qq) * 2048 + 1024 + cg] = hv;
        }
      }
    }
  }
}

// ============================================================================
extern "C" void kernel_launch(void* const* d_in, const int* in_sizes, int n_in,
                              void* d_out, int out_size, void* d_ws, size_t ws_size,
                              hipStream_t stream)
{
  const float* q    = (const float*)d_in[0];   // [1024,16,1024]
  const float* c    = (const float*)d_in[1];   // [2048,16,1024]
  const float* Win  = (const float*)d_in[2];   // [1024,1024]
  const float* Wout = (const float*)d_in[3];   // [1024,2048]

  char* ws = (char*)d_ws;
  const size_t MB = 1024u * 1024u;

  unsigned short* qh  = (unsigned short*)(ws);             // region A phase 1
  unsigned short* ch  = (unsigned short*)(ws);             // region A phase 2
  unsigned short* pb  = (unsigned short*)(ws);             // region A phase 3
  unsigned short* qbh = (unsigned short*)(ws + 64 * MB);   // region B phase 1
  unsigned short* qbl = (unsigned short*)(ws + 96 * MB);
  unsigned short* ct  = (unsigned short*)(ws + 64 * MB);   // region B phase 2
  unsigned short* cat = (unsigned short*)(ws + 128 * MB);  // region C
  unsigned short* Wh  = (unsigned short*)(ws + 192 * MB);
  unsigned short* Wl  = (unsigned short*)(ws + 194 * MB);
  unsigned short* Wo  = (unsigned short*)(ws + 196 * MB);

  unsigned short* ql  = (unsigned short*)d_out;            // out-region scratch
  unsigned short* cl  = (unsigned short*)d_out;            // out-region scratch
  float* out0  = (float*)d_out;                            // [1024,16,1024]
  float* score = (float*)d_out + 16777216;                 // [16,1024,2048]

  // phase 1: splits/converts needed by G1
  split_kernel<<<16384, 256, 0, stream>>>(q,    qh, ql,      4194304L);
  split_kernel<<<1024,  256, 0, stream>>>(Win,  Wh, Wl,      262144L);
  split_kernel<<<2048,  256, 0, stream>>>(Wout, Wo, nullptr, 524288L);

  // G1: qb = q @ Win^T  (split), M=16384 (rows q*16+b), N=1024, K=1024
  // tiles 64m x 4n; XCD sub-grid 8m x 4n
  gemm_kernel<1, 3><<<dim3(32, 8, 1), 512, 0, stream>>>(
      qh, ql, 0L, 1024L, Wh, Wl, 0L, 1024L,
      (void*)cat, 0L, 0L, qbh, qbl, 1024, 8, 4, 8);

  // phase 2: split c (q_hi/q_lo now dead)
  split_kernel<<<32768, 256, 0, stream>>>(c, ch, cl, 8388608L);

  // G2: logits[b][q][k] = qb[b,q,:] . c[k,b,:]  (split)
  // tiles 4m x 8n per batch; XCD sub-grid 2m x 2n (4MB hi+lo = one XCD L2)
  gemm_kernel<1, 0><<<dim3(4, 8, 16), 512, 0, stream>>>(
      qbh, qbl, 1024L, 16384L, ch, cl, 1024L, 16384L,
      (void*)score, 2097152L, 2048L, nullptr, nullptr, 1024, 2, 2, 2);

  // phase 3 (qb/c_hi/c_lo dead): transpose c, softmax in place
  transpose_kernel<<<dim3(32, 16, 16), 256, 0, stream>>>(c, ct);
  softmax_kernel<<<16384, 256, 0, stream>>>(score, pb);

  // G4: ctx[b][q][d] = P[b,q,:] . ct[b,d,:]  -> cat[...,0:1024] bf16
  // tiles 4m x 4n per batch; XCD sub-grid 1m x 2n
  gemm_kernel<0, 1><<<dim3(4, 4, 16), 512, 0, stream>>>(
      pb, nullptr, 2097152L, 2048L, ct, nullptr, 2097152L, 2048L,
      (void*)cat, 2097152L, 2048L, nullptr, nullptr, 2048, 1, 2, 4);

  // G5: out[(q*16+b)*1024+d] = tanh(cat[b*1024+q,:] . Wout[d,:])
  // tiles 64m x 4n; XCD sub-grid 8m x 4n
  gemm_kernel<0, 2><<<dim3(32, 8, 1), 512, 0, stream>>>(
      cat, nullptr, 0L, 2048L, Wo, nullptr, 0L, 2048L,
      (void*)out0, 0L, 0L, nullptr, nullptr, 2048, 8, 4, 8);

  (void)in_sizes; (void)n_in; (void)out_size; (void)ws_size;
}